// Round 4
// baseline (1177.360 us; speedup 1.0000x reference)
//
#include <hip/hip_runtime.h>
#include <stdint.h>

typedef unsigned short u16;
typedef __attribute__((ext_vector_type(8))) short short8;
typedef __attribute__((ext_vector_type(4))) float floatx4;

#define D_IN  512
#define M_TOT 24000
#define V_DIM 4000
#define V_PAD 4096
#define T_DIM 150
#define U_DIM 40

__device__ __forceinline__ u16 f2bf(float f) {
    union { float f; uint32_t u; } v; v.f = f;
    uint32_t r = v.u + 0x7FFF + ((v.u >> 16) & 1);   // RNE
    return (u16)(r >> 16);
}

// ---------------------------------------------------------------------------
// Kernel 1: enc = enc_state @ W_enc^T + b_enc   [600,512]
//           dec = dec_state @ W_prd^T + b_prd   [160,512]
// ---------------------------------------------------------------------------
__global__ void k_pre(const float* __restrict__ enc_state, const float* __restrict__ dec_state,
                      const float* __restrict__ W_enc, const float* __restrict__ b_enc,
                      const float* __restrict__ W_prd, const float* __restrict__ b_prd,
                      float* __restrict__ enc_o, float* __restrict__ dec_o)
{
    const float* Ag; const float* Wg; const float* bg; float* Og; int M;
    int by = blockIdx.y;
    if (by < 19) { Ag = enc_state; Wg = W_enc; bg = b_enc; Og = enc_o; M = 600; }
    else         { Ag = dec_state; Wg = W_prd; bg = b_prd; Og = dec_o; M = 160; by -= 19; }

    const int row0 = by * 32;
    const int col0 = blockIdx.x * 64;
    __shared__ float Ash[32][17];
    __shared__ float Bsh[64][17];
    const int tid = threadIdx.x;
    const int tr = tid & 31;
    const int tc = tid >> 5;
    float accv[8] = {0.f,0.f,0.f,0.f,0.f,0.f,0.f,0.f};

    for (int k0 = 0; k0 < D_IN; k0 += 16) {
        __syncthreads();
        #pragma unroll
        for (int s = 0; s < 2; ++s) {
            int idx = tid + s * 256;
            int r = idx >> 4, c = idx & 15;
            Ash[r][c] = (row0 + r < M) ? Ag[(size_t)(row0 + r) * D_IN + k0 + c] : 0.f;
        }
        #pragma unroll
        for (int s = 0; s < 4; ++s) {
            int idx = tid + s * 256;
            int r = idx >> 4, c = idx & 15;
            Bsh[r][c] = Wg[(size_t)(col0 + r) * D_IN + k0 + c];
        }
        __syncthreads();
        #pragma unroll
        for (int kk = 0; kk < 16; ++kk) {
            float a = Ash[tr][kk];
            #pragma unroll
            for (int j = 0; j < 8; ++j) accv[j] += a * Bsh[tc * 8 + j][kk];
        }
    }
    if (row0 + tr < M) {
        #pragma unroll
        for (int j = 0; j < 8; ++j)
            Og[(size_t)(row0 + tr) * D_IN + col0 + tc * 8 + j] = accv[j] + bg[col0 + tc * 8 + j];
    }
}

// ---------------------------------------------------------------------------
// Kernel 2: W_proj [4000,512] fp32 -> bf16 [4096,512], zero pad rows.
// ---------------------------------------------------------------------------
__global__ void k_wconv(const float* __restrict__ W_proj, u16* __restrict__ Wp)
{
    int gid = blockIdx.x * 256 + threadIdx.x;
    int idx8 = gid * 8;
    int row = idx8 >> 9;
    short8 w;
    if (row < V_DIM) {
        const float* p = W_proj + idx8;
        #pragma unroll
        for (int j = 0; j < 8; ++j) w[j] = (short)f2bf(p[j]);
    } else {
        w = (short8){0,0,0,0,0,0,0,0};
    }
    *(short8*)&Wp[idx8] = w;
}

// ---------------------------------------------------------------------------
// Kernel 3: joint[m,i] = tanh(enc[b,t,i] + dec[b,u,i]) -> bf16 [24000,512]
// ---------------------------------------------------------------------------
__global__ void k_joint(const float* __restrict__ enc_o, const float* __restrict__ dec_o,
                        u16* __restrict__ J)
{
    int m = blockIdx.x * 4 + (threadIdx.x >> 6);
    int i = (threadIdx.x & 63) * 8;
    int b = m / (T_DIM * U_DIM);
    int r = m % (T_DIM * U_DIM);
    int t = r / U_DIM, u = r % U_DIM;
    const float4* e = (const float4*)(enc_o + (size_t)(b * T_DIM + t) * D_IN + i);
    const float4* d = (const float4*)(dec_o + (size_t)(b * U_DIM + u) * D_IN + i);
    float4 e0 = e[0], e1 = e[1], d0 = d[0], d1 = d[1];
    short8 w;
    w[0] = (short)f2bf(tanhf(e0.x + d0.x));
    w[1] = (short)f2bf(tanhf(e0.y + d0.y));
    w[2] = (short)f2bf(tanhf(e0.z + d0.z));
    w[3] = (short)f2bf(tanhf(e0.w + d0.w));
    w[4] = (short)f2bf(tanhf(e1.x + d1.x));
    w[5] = (short)f2bf(tanhf(e1.y + d1.y));
    w[6] = (short)f2bf(tanhf(e1.z + d1.z));
    w[7] = (short)f2bf(tanhf(e1.w + d1.w));
    *(short8*)&J[(size_t)m * D_IN + i] = w;
}

// ---------------------------------------------------------------------------
// Kernel 4 (fused GEMM + log-softmax), v4 — anti-spill build:
// Block owns 16 complete rows (all 4096 cols in regs): LSE in-register,
// single nontemporal C write. 8 waves x 512 cols each (32 16x16 tiles).
// v2/v3 post-mortem: VGPR_Count 108/124 < 128 => acc[] itself was spilled to
// scratch (extra ~140MB WRITE_SIZE) — scratch-bound, not latency-bound.
// v4 register plan (hard budget 256, launch_bounds(512,2)):
//   acc[32] floatx4 ......... 128
//   b0[8]+b1[8] short8 ...... 64   (explicit 2-buffer B rotation, global->VGPR)
//   A-frag transient ........ ~8   (ds_read right before each MFMA, NOT hoisted)
//   addressing/misc ......... ~20  => ~220, no spill.
// No branches in K-loop (Wp pad rows zeroed). No inline asm / global_load_lds:
// compiler emits counted vmcnt() from register deps; refill for step s+2 is
// issued after the last MFMA consuming that parity => loads for s+1/s+2 are
// in flight during each step's MFMA chain.
// ---------------------------------------------------------------------------
__global__ __launch_bounds__(512, 2) void k_fused(const u16* __restrict__ J,
                                                  const u16* __restrict__ Bt,
                                                  const float* __restrict__ bias,
                                                  float* __restrict__ C)
{
    __shared__ u16 Alds[8192];            // 16 KB, XOR-swizzled A tile
    __shared__ float sered[8][16];

    const int tid  = threadIdx.x;
    const int row0 = blockIdx.x * 16;     // 1500 * 16 = 24000 exact
    const int wave = tid >> 6;
    const int lane = tid & 63;
    const int lrow = lane & 15;           // A-row / B-row(=out col) in frag
    const int lq   = lane >> 4;           // k-quarter; out row = lq*4+reg
    const int wc0  = wave << 9;           // wave col base

    // ---- stage A: coalesced global read, XOR-swizzled LDS write ----
    // byte addr = row*1024 + ((kch*16) ^ ((row&7)<<4))
    #pragma unroll
    for (int s = 0; s < 2; ++s) {
        int c = tid + s * 512;
        int row = c >> 6, kch = c & 63;
        short8 v = *(const short8*)(J + (size_t)(row0 + row) * D_IN + kch * 8);
        *(short8*)((char*)Alds + row * 1024 + ((kch * 16) ^ ((row & 7) << 4))) = v;
    }
    __syncthreads();

    floatx4 acc[32];
    #pragma unroll
    for (int ct = 0; ct < 32; ++ct) acc[ct] = (floatx4){0.f, 0.f, 0.f, 0.f};

    // per-lane B base: row (wc0+lrow), k offset lq*8
    const u16* gw = Bt + (size_t)(wc0 + lrow) * D_IN + lq * 8;

    short8 b0[8], b1[8];
    // prologue: step 0 -> b0, step 1 -> b1
    #pragma unroll
    for (int j = 0; j < 8; ++j) b0[j] = *(const short8*)(gw + j * 32);
    #pragma unroll
    for (int j = 0; j < 8; ++j) b1[j] = *(const short8*)(gw + 256 + j * 32);

    // main loop: 64 steps = 32 tiles x 2 half-K; step s uses parity s&1
    #pragma unroll
    for (int s = 0; s < 64; ++s) {
        const int ct = s >> 1;
        const int h  = s & 1;
        // 8 MFMAs consuming buffer of this parity; A-frags fresh from LDS
        #pragma unroll
        for (int j = 0; j < 8; ++j) {
            const int kch = ((h * 8 + j) << 2) + lq;
            short8 a = *(const short8*)((const char*)Alds + lrow * 1024 +
                                        ((kch * 16) ^ ((lrow & 7) << 4)));
            if (h == 0)
                acc[ct] = __builtin_amdgcn_mfma_f32_16x16x32_bf16(a, b0[j], acc[ct], 0, 0, 0);
            else
                acc[ct] = __builtin_amdgcn_mfma_f32_16x16x32_bf16(a, b1[j], acc[ct], 0, 0, 0);
        }
        // refill this parity for step s+2 (in flight across step s+1)
        if (s + 2 < 64) {
            const u16* g = gw + (size_t)((s + 2) >> 1) * (16 * D_IN) + ((s + 2) & 1) * 256;
            #pragma unroll
            for (int j = 0; j < 8; ++j) {
                if (h == 0) b0[j] = *(const short8*)(g + j * 32);
                else        b1[j] = *(const short8*)(g + j * 32);
            }
        }
    }

    // ---- epilogue: bias + per-lane exp-sums ----
    float se[4] = {0.f, 0.f, 0.f, 0.f};
    #pragma unroll
    for (int ct = 0; ct < 32; ++ct) {
        int cc = wc0 + ct * 16;
        if (cc < V_DIM) {
            float bv = bias[cc + lrow];
            #pragma unroll
            for (int r = 0; r < 4; ++r) {
                float lg = acc[ct][r] + bv;
                acc[ct][r] = lg;
                se[r] += __expf(lg);
            }
        }
    }
    #pragma unroll
    for (int m = 1; m < 16; m <<= 1) {
        #pragma unroll
        for (int r = 0; r < 4; ++r) se[r] += __shfl_xor(se[r], m, 64);
    }
    if (lrow == 0) {
        #pragma unroll
        for (int r = 0; r < 4; ++r) sered[wave][lq * 4 + r] = se[r];
    }
    __syncthreads();
    float lse[4];
    #pragma unroll
    for (int r = 0; r < 4; ++r) {
        float tot = 0.f;
        #pragma unroll
        for (int w = 0; w < 8; ++w) tot += sered[w][lq * 4 + r];
        lse[r] = __logf(tot);
    }

    // ---- single write of C (nontemporal: C never re-read) ----
    float* crow = C + (size_t)(row0 + lq * 4) * V_DIM + lrow;
    #pragma unroll
    for (int ct = 0; ct < 32; ++ct) {
        int cc = wc0 + ct * 16;
        if (cc < V_DIM) {
            #pragma unroll
            for (int r = 0; r < 4; ++r)
                __builtin_nontemporal_store(acc[ct][r] - lse[r], crow + (size_t)r * V_DIM + cc);
        }
    }
}

extern "C" void kernel_launch(void* const* d_in, const int* in_sizes, int n_in,
                              void* d_out, int out_size, void* d_ws, size_t ws_size,
                              hipStream_t stream)
{
    const float* enc_state = (const float*)d_in[0];
    const float* dec_state = (const float*)d_in[1];
    const float* W_enc     = (const float*)d_in[2];
    const float* b_enc     = (const float*)d_in[3];
    const float* W_prd     = (const float*)d_in[4];
    const float* b_prd     = (const float*)d_in[5];
    const float* W_proj    = (const float*)d_in[6];
    const float* b_proj    = (const float*)d_in[7];
    float* out = (float*)d_out;

    char* ws = (char*)d_ws;
    float* enc_o = (float*)(ws);                  // 1,228,800 B
    float* dec_o = (float*)(ws + 1228800);        //   327,680 B
    u16*   Wp    = (u16*)  (ws + 1556480);        // 4,194,304 B
    u16*   J     = (u16*)  (ws + 5750784);        // 24,576,000 B

    k_pre  <<<dim3(8, 24), 256, 0, stream>>>(enc_state, dec_state, W_enc, b_enc, W_prd, b_prd, enc_o, dec_o);
    k_wconv<<<dim3(1024),  256, 0, stream>>>(W_proj, Wp);
    k_joint<<<dim3(6000),  256, 0, stream>>>(enc_o, dec_o, J);
    k_fused<<<dim3(1500),  512, 0, stream>>>(J, Wp, b_proj, out);
}

// Round 5
// 742.006 us; speedup vs baseline: 1.5867x; 1.5867x over previous
//
#include <hip/hip_runtime.h>
#include <stdint.h>

typedef unsigned short u16;
typedef __attribute__((ext_vector_type(8))) short short8;
typedef __attribute__((ext_vector_type(4))) float floatx4;

#define D_IN  512
#define M_TOT 24000
#define V_DIM 4000
#define V_PAD 4096
#define T_DIM 150
#define U_DIM 40

// dynamic LDS for k_fused
#define SMEM_A   16384                     // A tile, XOR-swizzled
#define SMEM_B   131072                    // B: [wave 8][buf 2][8 KB half-tile]
#define SMEM_TOT (SMEM_A + SMEM_B + 512)

__device__ __forceinline__ u16 f2bf(float f) {
    union { float f; uint32_t u; } v; v.f = f;
    uint32_t r = v.u + 0x7FFF + ((v.u >> 16) & 1);   // RNE
    return (u16)(r >> 16);
}

__device__ __forceinline__ void gld_lds16(const u16* g, u16* l) {
    __builtin_amdgcn_global_load_lds(
        (const __attribute__((address_space(1))) void*)g,
        (__attribute__((address_space(3))) void*)l,
        16, 0, 0);                          // lane's 16B -> ldsbase + lane*16
}

// ---------------------------------------------------------------------------
// Kernel 1: enc = enc_state @ W_enc^T + b_enc   [600,512]
//           dec = dec_state @ W_prd^T + b_prd   [160,512]
// ---------------------------------------------------------------------------
__global__ void k_pre(const float* __restrict__ enc_state, const float* __restrict__ dec_state,
                      const float* __restrict__ W_enc, const float* __restrict__ b_enc,
                      const float* __restrict__ W_prd, const float* __restrict__ b_prd,
                      float* __restrict__ enc_o, float* __restrict__ dec_o)
{
    const float* Ag; const float* Wg; const float* bg; float* Og; int M;
    int by = blockIdx.y;
    if (by < 19) { Ag = enc_state; Wg = W_enc; bg = b_enc; Og = enc_o; M = 600; }
    else         { Ag = dec_state; Wg = W_prd; bg = b_prd; Og = dec_o; M = 160; by -= 19; }

    const int row0 = by * 32;
    const int col0 = blockIdx.x * 64;
    __shared__ float Ash[32][17];
    __shared__ float Bsh[64][17];
    const int tid = threadIdx.x;
    const int tr = tid & 31;
    const int tc = tid >> 5;
    float accv[8] = {0.f,0.f,0.f,0.f,0.f,0.f,0.f,0.f};

    for (int k0 = 0; k0 < D_IN; k0 += 16) {
        __syncthreads();
        #pragma unroll
        for (int s = 0; s < 2; ++s) {
            int idx = tid + s * 256;
            int r = idx >> 4, c = idx & 15;
            Ash[r][c] = (row0 + r < M) ? Ag[(size_t)(row0 + r) * D_IN + k0 + c] : 0.f;
        }
        #pragma unroll
        for (int s = 0; s < 4; ++s) {
            int idx = tid + s * 256;
            int r = idx >> 4, c = idx & 15;
            Bsh[r][c] = Wg[(size_t)(col0 + r) * D_IN + k0 + c];
        }
        __syncthreads();
        #pragma unroll
        for (int kk = 0; kk < 16; ++kk) {
            float a = Ash[tr][kk];
            #pragma unroll
            for (int j = 0; j < 8; ++j) accv[j] += a * Bsh[tc * 8 + j][kk];
        }
    }
    if (row0 + tr < M) {
        #pragma unroll
        for (int j = 0; j < 8; ++j)
            Og[(size_t)(row0 + tr) * D_IN + col0 + tc * 8 + j] = accv[j] + bg[col0 + tc * 8 + j];
    }
}

// ---------------------------------------------------------------------------
// Kernel 2: W_proj [4000,512] fp32 -> bf16 [4096,512], zero pad rows.
// ---------------------------------------------------------------------------
__global__ void k_wconv(const float* __restrict__ W_proj, u16* __restrict__ Wp)
{
    int gid = blockIdx.x * 256 + threadIdx.x;
    int idx8 = gid * 8;
    int row = idx8 >> 9;
    short8 w;
    if (row < V_DIM) {
        const float* p = W_proj + idx8;
        #pragma unroll
        for (int j = 0; j < 8; ++j) w[j] = (short)f2bf(p[j]);
    } else {
        w = (short8){0,0,0,0,0,0,0,0};
    }
    *(short8*)&Wp[idx8] = w;
}

// ---------------------------------------------------------------------------
// Kernel 3: joint[m,i] = tanh(enc[b,t,i] + dec[b,u,i]) -> bf16 [24000,512]
// ---------------------------------------------------------------------------
__global__ void k_joint(const float* __restrict__ enc_o, const float* __restrict__ dec_o,
                        u16* __restrict__ J)
{
    int m = blockIdx.x * 4 + (threadIdx.x >> 6);
    int i = (threadIdx.x & 63) * 8;
    int b = m / (T_DIM * U_DIM);
    int r = m % (T_DIM * U_DIM);
    int t = r / U_DIM, u = r % U_DIM;
    const float4* e = (const float4*)(enc_o + (size_t)(b * T_DIM + t) * D_IN + i);
    const float4* d = (const float4*)(dec_o + (size_t)(b * U_DIM + u) * D_IN + i);
    float4 e0 = e[0], e1 = e[1], d0 = d[0], d1 = d[1];
    short8 w;
    w[0] = (short)f2bf(tanhf(e0.x + d0.x));
    w[1] = (short)f2bf(tanhf(e0.y + d0.y));
    w[2] = (short)f2bf(tanhf(e0.z + d0.z));
    w[3] = (short)f2bf(tanhf(e0.w + d0.w));
    w[4] = (short)f2bf(tanhf(e1.x + d1.x));
    w[5] = (short)f2bf(tanhf(e1.y + d1.y));
    w[6] = (short)f2bf(tanhf(e1.z + d1.z));
    w[7] = (short)f2bf(tanhf(e1.w + d1.w));
    *(short8*)&J[(size_t)m * D_IN + i] = w;
}

// ---------------------------------------------------------------------------
// Kernel 4 (fused GEMM + log-softmax), v5 — coalesced B streaming:
// v2/v3/v4 post-mortem: all three engines tied at ~810us because B was
// fetched in FRAGMENT order (16B/lane, rows 1KB apart) = 16 half-line L2
// sector requests per wave-load -> L2 request-rate bound at ~7.3TB/s
// effective. v5 fetches B COALESCED (1KB contiguous per global_load_lds,
// 8 fully-used 128B lines) into per-wave double-buffered LDS slices
// (pre-swizzled global source, linear DMA dest), then fragments via
// ds_read_b128 with the XOR swizzle proven on the A tile.
// Counted vmcnt(8) keeps one half-tile DMA in flight; lgkmcnt(0)+
// sched_barrier fences the WAR on buffer reuse (v3 machinery, kept).
// Regs: acc 128 (AGPR) + af 64 + bfr 32 + addr ~25 -> fits like v3 (124).
// Expected regime: L2 streaming bound, ~31us/block, ~200-280us total.
// ---------------------------------------------------------------------------
__global__ __launch_bounds__(512, 2) void k_fused(const u16* __restrict__ J,
                                                  const u16* __restrict__ Bt,
                                                  const float* __restrict__ bias,
                                                  float* __restrict__ C)
{
    extern __shared__ char smem[];
    char* Alds = smem;                                  // 16 KB
    u16*  Blds = (u16*)(smem + SMEM_A);                 // 128 KB
    float (*sered)[16] = (float(*)[16])(smem + SMEM_A + SMEM_B);

    const int tid  = threadIdx.x;
    const int row0 = blockIdx.x * 16;                   // 1500*16 = 24000
    const int wave = tid >> 6;
    const int lane = tid & 63;
    const int lrow = lane & 15;                         // frag row (=out col)
    const int lq   = lane >> 4;                         // k-quarter
    const int wc0  = wave << 9;                         // wave col base

    // ---- stage A: coalesced global read, XOR-swizzled LDS write ----
    #pragma unroll
    for (int s = 0; s < 2; ++s) {
        int c = tid + s * 512;
        int row = c >> 6, kch = c & 63;
        short8 v = *(const short8*)(J + (size_t)(row0 + row) * D_IN + kch * 8);
        *(short8*)(Alds + row * 1024 + ((kch * 16) ^ ((row & 7) << 4))) = v;
    }
    __syncthreads();

    // ---- hoist all 16 A-frags to registers (64 VGPR) ----
    short8 af[16];
    #pragma unroll
    for (int kk = 0; kk < 16; ++kk) {
        int kch = (kk << 2) + lq;
        af[kk] = *(const short8*)(Alds + lrow * 1024 + ((kch * 16) ^ ((lrow & 7) << 4)));
    }

    floatx4 acc[32];
    #pragma unroll
    for (int ct = 0; ct < 32; ++ct) acc[ct] = (floatx4){0.f, 0.f, 0.f, 0.f};

    // ---- coalesced B DMA setup ----
    // stage(s), instr i in 0..7: lane l loads 16B from
    //   Bt row (wc0 + (s>>1)*16 + r0), r0 = 2i + (l>>5)
    //   byte-in-row: (s&1)*512 + (((l&31)*16) ^ ((r0&7)<<4))   [pre-swizzle]
    // into LDS linear slot  Bw + (s&1)*8192B + i*1024B + l*16B.
    // Reader un-swizzles with the same XOR -> net identity (m173 pattern).
    const int lhi   = lane >> 5;
    const int llo16 = (lane & 31) * 16;
    int soff[8];                        // per-lane byte offset: r0*1024 + swz
    #pragma unroll
    for (int i = 0; i < 8; ++i) {
        int r0 = 2 * i + lhi;
        soff[i] = r0 * 1024 + (llo16 ^ ((r0 & 7) << 4));
    }
    const char* gB = (const char*)Bt + (size_t)wc0 * 1024;   // wave col base
    u16* Bw = Blds + wave * 8192;                            // 2 bufs x 4096 u16

#define STAGE(s)                                                               \
    {                                                                          \
        const char* gbase = gB + (size_t)((s) >> 1) * 16384 + ((s) & 1) * 512; \
        u16* dbase = Bw + ((s) & 1) * 4096;                                    \
        _Pragma("unroll")                                                      \
        for (int i = 0; i < 8; ++i)                                            \
            gld_lds16((const u16*)(gbase + soff[i]), dbase + i * 512);         \
    }

    // prologue: half-tiles 0 and 1 in flight
    STAGE(0);
    STAGE(1);

    // ---- main loop: 64 half-tile steps, 1-step DMA lookahead ----
    #pragma unroll
    for (int s = 0; s < 64; ++s) {
        const int ct = s >> 1;
        const int h  = s & 1;
        u16* Bb = Bw + h * 4096;
        if (s == 63) asm volatile("s_waitcnt vmcnt(0)" ::: "memory");
        else         asm volatile("s_waitcnt vmcnt(8)" ::: "memory");
        short8 bfr[8];
        #pragma unroll
        for (int j = 0; j < 8; ++j)
            bfr[j] = *(const short8*)((const char*)Bb + lrow * 512 +
                                      ((j * 64 + lq * 16) ^ ((lrow & 7) << 4)));
        // buffer must be fully read before its refill can land
        asm volatile("s_waitcnt lgkmcnt(0)" ::: "memory");
        __builtin_amdgcn_sched_barrier(0);
        if (s + 2 < 64) STAGE(s + 2);
        #pragma unroll
        for (int j = 0; j < 8; ++j)
            acc[ct] = __builtin_amdgcn_mfma_f32_16x16x32_bf16(af[h * 8 + j], bfr[j], acc[ct], 0, 0, 0);
    }
#undef STAGE

    // ---- epilogue: bias + per-lane exp-sums ----
    float se[4] = {0.f, 0.f, 0.f, 0.f};
    #pragma unroll
    for (int ct = 0; ct < 32; ++ct) {
        int cc = wc0 + ct * 16;
        if (cc < V_DIM) {
            float bv = bias[cc + lrow];
            #pragma unroll
            for (int r = 0; r < 4; ++r) {
                float lg = acc[ct][r] + bv;
                acc[ct][r] = lg;
                se[r] += __expf(lg);
            }
        }
    }
    #pragma unroll
    for (int m = 1; m < 16; m <<= 1) {
        #pragma unroll
        for (int r = 0; r < 4; ++r) se[r] += __shfl_xor(se[r], m, 64);
    }
    if (lrow == 0) {
        #pragma unroll
        for (int r = 0; r < 4; ++r) sered[wave][lq * 4 + r] = se[r];
    }
    __syncthreads();
    float lse[4];
    #pragma unroll
    for (int r = 0; r < 4; ++r) {
        float tot = 0.f;
        #pragma unroll
        for (int w = 0; w < 8; ++w) tot += sered[w][lq * 4 + r];
        lse[r] = __logf(tot);
    }

    // ---- single write of C (nontemporal: C never re-read) ----
    float* crow = C + (size_t)(row0 + lq * 4) * V_DIM + lrow;
    #pragma unroll
    for (int ct = 0; ct < 32; ++ct) {
        int cc = wc0 + ct * 16;
        if (cc < V_DIM) {
            #pragma unroll
            for (int r = 0; r < 4; ++r)
                __builtin_nontemporal_store(acc[ct][r] - lse[r], crow + (size_t)r * V_DIM + cc);
        }
    }
}

extern "C" void kernel_launch(void* const* d_in, const int* in_sizes, int n_in,
                              void* d_out, int out_size, void* d_ws, size_t ws_size,
                              hipStream_t stream)
{
    const float* enc_state = (const float*)d_in[0];
    const float* dec_state = (const float*)d_in[1];
    const float* W_enc     = (const float*)d_in[2];
    const float* b_enc     = (const float*)d_in[3];
    const float* W_prd     = (const float*)d_in[4];
    const float* b_prd     = (const float*)d_in[5];
    const float* W_proj    = (const float*)d_in[6];
    const float* b_proj    = (const float*)d_in[7];
    float* out = (float*)d_out;

    char* ws = (char*)d_ws;
    float* enc_o = (float*)(ws);                  // 1,228,800 B
    float* dec_o = (float*)(ws + 1228800);        //   327,680 B
    u16*   Wp    = (u16*)  (ws + 1556480);        // 4,194,304 B
    u16*   J     = (u16*)  (ws + 5750784);        // 24,576,000 B

    static int cfg = 0;
    if (!cfg) {
        hipFuncSetAttribute((const void*)k_fused,
                            hipFuncAttributeMaxDynamicSharedMemorySize, SMEM_TOT);
        cfg = 1;
    }

    k_pre  <<<dim3(8, 24), 256, 0, stream>>>(enc_state, dec_state, W_enc, b_enc, W_prd, b_prd, enc_o, dec_o);
    k_wconv<<<dim3(1024),  256, 0, stream>>>(W_proj, Wp);
    k_joint<<<dim3(6000),  256, 0, stream>>>(enc_o, dec_o, J);
    k_fused<<<dim3(1500),  512, SMEM_TOT, stream>>>(J, Wp, b_proj, out);
}